// Round 4
// baseline (239.571 us; speedup 1.0000x reference)
//
#include <hip/hip_runtime.h>
#include <hip/hip_bf16.h>

// Sobel |gx|+|gy|+eps, SAME zero padding. Input (32,1,1024,1024) fp32.
//
// R4: batch-loaded register tile. R3 was latency-bound (VALUBusy 11%, real BW
// 2.5 TB/s, both pipes idle): its 1-deep prefetch chain exposed a vmcnt wait
// every iteration (~3 loads in flight per wave). Here each thread loads ALL
// R+2=10 rows (1 dwordx4 + 2 dword each, 30 independent VMEM instrs) up
// front, then computes 8 output rows from registers. No carried dependency,
// no per-iteration drain. Regular stores (NT removed — NT retirement on the
// shared vmcnt was a suspect serializer). XCD swizzle: block b -> strip
// (b%8)*512 + b/8, so each XCD owns a contiguous strip range and halo rows
// hit its private L2.

#define W 1024
#define H 1024
#define R 8           // output rows per block strip (128 strips/image)
#define EPS 1e-5f

typedef float v4f __attribute__((ext_vector_type(4)));

__device__ __forceinline__ void loadrow(const float* __restrict__ base, int y,
                                        int x0, float* dst) {
    if (y < 0 || y >= H) {
        dst[0] = dst[1] = dst[2] = dst[3] = dst[4] = dst[5] = 0.f;
        return;
    }
    const float* r = base + (size_t)y * W;
    v4f v = *(const v4f*)(r + x0);
    dst[1] = v.x; dst[2] = v.y; dst[3] = v.z; dst[4] = v.w;
    dst[0] = (x0 > 0) ? r[x0 - 1] : 0.f;
    dst[5] = (x0 + 4 < W) ? r[x0 + 4] : 0.f;
}

__global__ __launch_bounds__(256) void sobel_kernel(const float* __restrict__ in,
                                                    float* __restrict__ out) {
    const int b = blockIdx.x;                  // 0..4095
    const int s = ((b & 7) << 9) | (b >> 3);   // contiguous strips per XCD
    const int img = s >> 7;                    // 128 strips per image
    const int ty = (s & 127) << 3;             // first output row (*R)
    const int x0 = threadIdx.x << 2;

    const float* base = in + (size_t)img * (W * H);
    float* obase = out + (size_t)img * (W * H);

    // Load the entire 10-row halo tile into registers, all loads independent.
    float rows[R + 2][6];
#pragma unroll
    for (int r = 0; r < R + 2; ++r) {
        loadrow(base, ty - 1 + r, x0, rows[r]);
    }

#pragma unroll
    for (int i = 0; i < R; ++i) {
        const float* T = rows[i];
        const float* M = rows[i + 1];
        const float* B = rows[i + 2];
        v4f o;
#pragma unroll
        for (int j = 0; j < 4; ++j) {
            // Sobel X: [[-1,0,1],[-2,0,2],[-1,0,1]]
            float gx = (T[j + 2] - T[j]) + 2.0f * (M[j + 2] - M[j]) + (B[j + 2] - B[j]);
            // Sobel Y: [[-1,-2,-1],[0,0,0],[1,2,1]]
            float gy = (B[j] + 2.0f * B[j + 1] + B[j + 2]) - (T[j] + 2.0f * T[j + 1] + T[j + 2]);
            o[j] = fabsf(gx) + fabsf(gy) + EPS;
        }
        *(v4f*)(obase + (size_t)(ty + i) * W + x0) = o;
    }
}

extern "C" void kernel_launch(void* const* d_in, const int* in_sizes, int n_in,
                              void* d_out, int out_size, void* d_ws, size_t ws_size,
                              hipStream_t stream) {
    const float* x = (const float*)d_in[0];
    float* out = (float*)d_out;
    const int N = 32;
    dim3 grid(N * (H / R));   // 32 * 128 = 4096 blocks
    dim3 block(256);
    sobel_kernel<<<grid, block, 0, stream>>>(x, out);
}